// Round 10
// baseline (443.278 us; speedup 1.0000x reference)
//
#include <hip/hip_runtime.h>

// CRF forward (partition fn), B=512, T=512, L=102 (start=100, stop=101).
// R10 = R9 with the macro-paste bug fixed (DOTA received computed k ->
// "sq4*(a)+0" integer garbage instead of sq_k; preprocessor does no math).
// Design: NO LDS in the step loop. Q (102 f16 probs packed as 51 half2)
// broadcast each step via 51 v_readlane -> SGPRs; v_dot2_f32_f16 takes the
// SGPR directly. Serial path: dot -> mul -> cvt_pk -> readlane -> dot.
// Linear-domain recurrence with shadow normalization (R8-proven):
//   q_t = E(t)*rcp(R)*2^-8 * dot(Mhat, q_{t-1}), E*invR folded off-path.

typedef _Float16 half2_t __attribute__((ext_vector_type(2)));

#define CRF_L 102
#define CRF_RP 104
#define CRF_START 100
#define CRF_STOP 101
#define NEG_BIG (-1.0e30f)
#define LN2F 0.6931471805599453f

#define REP51(X) X(0) X(1) X(2) X(3) X(4) X(5) X(6) X(7) X(8) X(9) \
                 X(10) X(11) X(12) X(13) X(14) X(15) X(16) X(17) X(18) X(19) \
                 X(20) X(21) X(22) X(23) X(24) X(25) X(26) X(27) X(28) X(29) \
                 X(30) X(31) X(32) X(33) X(34) X(35) X(36) X(37) X(38) X(39) \
                 X(40) X(41) X(42) X(43) X(44) X(45) X(46) X(47) X(48) X(49) X(50)

// literal-index dot list with accumulator rotation (k % 4) hand-written:
#define DOT_ALL(X) \
    X(0,c0,d0)  X(1,c1,d1)  X(2,c2,d2)  X(3,c3,d3) \
    X(4,c0,d0)  X(5,c1,d1)  X(6,c2,d2)  X(7,c3,d3) \
    X(8,c0,d0)  X(9,c1,d1)  X(10,c2,d2) X(11,c3,d3) \
    X(12,c0,d0) X(13,c1,d1) X(14,c2,d2) X(15,c3,d3) \
    X(16,c0,d0) X(17,c1,d1) X(18,c2,d2) X(19,c3,d3) \
    X(20,c0,d0) X(21,c1,d1) X(22,c2,d2) X(23,c3,d3) \
    X(24,c0,d0) X(25,c1,d1) X(26,c2,d2) X(27,c3,d3) \
    X(28,c0,d0) X(29,c1,d1) X(30,c2,d2) X(31,c3,d3) \
    X(32,c0,d0) X(33,c1,d1) X(34,c2,d2) X(35,c3,d3) \
    X(36,c0,d0) X(37,c1,d1) X(38,c2,d2) X(39,c3,d3) \
    X(40,c0,d0) X(41,c1,d1) X(42,c2,d2) X(43,c3,d3) \
    X(44,c0,d0) X(45,c1,d1) X(46,c2,d2) X(47,c3,d3) \
    X(48,c0,d0) X(49,c1,d1) X(50,c2,d2)

#define FDOT2(a, b, c) __builtin_amdgcn_fdot2((a), (b), (c), false)

template <int CTRL>
__device__ __forceinline__ float dpp_add_step(float x) {
    int xi = __builtin_bit_cast(int, x);
    int yi = __builtin_amdgcn_update_dpp(0, xi, CTRL, 0xf, 0xf, true);
    return x + __builtin_bit_cast(float, yi);
}
__device__ __forceinline__ float wave_sum64(float v) {
    v = dpp_add_step<0x111>(v);  // row_shr:1
    v = dpp_add_step<0x112>(v);  // row_shr:2
    v = dpp_add_step<0x114>(v);  // row_shr:4
    v = dpp_add_step<0x118>(v);  // row_shr:8
    v = dpp_add_step<0x142>(v);  // row_bcast:15
    v = dpp_add_step<0x143>(v);  // row_bcast:31
    return __builtin_bit_cast(float,
        __builtin_amdgcn_readlane(__builtin_bit_cast(int, v), 63));
}

__device__ __forceinline__ half2_t mk2(const float* rowp, int k, float rmx) {
    float e0 = __expf(rowp[k + 0] - rmx);
    float e1 = __expf(rowp[k + 1] - rmx);
    return (half2_t){(_Float16)e0, (_Float16)e1};
}

__attribute__((amdgpu_waves_per_eu(1, 1)))
__launch_bounds__(64)
__global__ void crf_forward_kernel(const float* __restrict__ logits,
                                   const float* __restrict__ trans,
                                   const int* __restrict__ lens,
                                   float* __restrict__ out,
                                   int B, int T) {
    const int b    = blockIdx.x;
    const int lane = threadIdx.x;          // 0..63
    const int r0   = 2 * lane;
    const int r1   = 2 * lane + 1;
    const bool valid = (lane < 51);        // rows 0..101 on lanes 0..50

    __shared__ __align__(16) float TS[CRF_L * CRF_RP];   // trans staging

    // ---- stage trans into LDS (coalesced, setup-only) ----
    #pragma unroll 4
    for (int r = 0; r < CRF_L; ++r)
        for (int c = lane; c < CRF_L; c += 64)
            TS[CRF_RP * r + c] = trans[CRF_L * r + c];
    __builtin_amdgcn_wave_barrier();

    // ---- rowmax + pack Mhat rows into 102 named half2 VGPRs ----
    const float* rowA = &TS[CRF_RP * (valid ? r0 : 0)];
    const float* rowB = &TS[CRF_RP * (valid ? r1 : 0)];
    float rmax0 = NEG_BIG, rmax1 = NEG_BIG;
    #pragma unroll
    for (int k = 0; k < CRF_L; ++k) {
        rmax0 = fmaxf(rmax0, rowA[k]);
        rmax1 = fmaxf(rmax1, rowB[k]);
    }

#define DECLM(k) half2_t ma##k, mb##k;
    REP51(DECLM)
#undef DECLM
#define PACKM(k) ma##k = mk2(rowA, 2*(k), rmax0); mb##k = mk2(rowB, 2*(k), rmax1);
    REP51(PACKM)
#undef PACKM

    // E uses logit + rowmax; invalid lanes get -inf so E==0 -> q==0 always
    const float erm0 = valid ? rmax0 : NEG_BIG;
    const float erm1 = valid ? rmax1 : NEG_BIG;

    const int len = min(lens[b], T);
    const float* lg = logits + (size_t)b * (size_t)T * (size_t)CRF_L;
    const int loff = valid ? r0 : 0;

    // depth-3 logit prefetch; E*invR prepared one step ahead (off-path)
    float2 l0  = *reinterpret_cast<const float2*>(lg + loff);
    float2 lgB = *reinterpret_cast<const float2*>(lg + (size_t)min(1, T - 1) * CRF_L + loff);
    float2 lgC = *reinterpret_cast<const float2*>(lg + (size_t)min(2, T - 1) * CRF_L + loff);

    // scale bookkeeping (R8-proven): invRs applied at next step carries 2^-8
    float invRs  = 0.00390625f;              // 2^-8 * rcp(sum Q0 = 1)
    float log2Rs = 0.f;
    float Lacc   = 0.f;
    float2 EcI = make_float2(__expf(l0.x + erm0) * invRs,
                             __expf(l0.y + erm1) * invRs);

    // Q0 = onehot(START): lane 50 holds rows 100,101 -> (1, 0)
    float q0 = 0.f, q1 = 0.f;
    half2_t qp0 = (half2_t){(_Float16)((r0 == CRF_START) ? 1.f : 0.f),
                            (_Float16)0.f};
    int qbits = __builtin_bit_cast(int, qp0);

    for (int t = 0; t < len; ++t) {
        // ---- broadcast all 51 q-pairs to SGPRs (readlane, literal idx) ----
#define RDL(k) int sq##k = __builtin_amdgcn_readlane(qbits, k);
        REP51(RDL)
#undef RDL

        // ---- dot(Mhat[row,:], Q[:]) both rows: 102 dot2, SGPR operand ----
        float c0 = 0.f, c1 = 0.f, c2 = 0.f, c3 = 0.f;
        float d0 = 0.f, d1 = 0.f, d2 = 0.f, d3 = 0.f;
#define DOTA(k, ci, di) { half2_t qh = __builtin_bit_cast(half2_t, sq##k); \
        ci = FDOT2(ma##k, qh, ci); di = FDOT2(mb##k, qh, di); }
        DOT_ALL(DOTA)
#undef DOTA
        float dot0 = (c0 + c1) + (c2 + c3);
        float dot1 = (d0 + d1) + (d2 + d3);

        // ---- on-path: 1 mul + pack (E*invR premultiplied off-path) ----
        Lacc += log2Rs + 8.0f;               // factor R*2^8 applied this step
        q0 = dot0 * EcI.x;
        q1 = dot1 * EcI.y;
        half2_t qp = (half2_t){(_Float16)q0, (_Float16)q1};
        qbits = __builtin_bit_cast(int, qp);

        // ---- shadow work for NEXT step (off the serial path) ----
        float R = wave_sum64(q0 + q1);       // lanes>=51 contribute 0
        R = fmaxf(R, 1e-30f);
        invRs  = __builtin_amdgcn_rcpf(R) * 0.00390625f;
        log2Rs = __log2f(R);

        EcI.x = __expf(lgB.x + erm0) * invRs;   // E*invR for step t+1
        EcI.y = __expf(lgB.y + erm1) * invRs;
        lgB = lgC;
        lgC = *reinterpret_cast<const float2*>(lg + (size_t)min(t + 3, T - 1) * CRF_L + loff);
    }

    // ---- epilogue: out = ln2*Lacc + log(sum_j Q_j * exp(trans[STOP,j])) ----
    float ts0 = TS[CRF_RP * CRF_STOP + (valid ? r0 : 0)];
    float ts1 = TS[CRF_RP * CRF_STOP + (valid ? r1 : 0)];
    float e;
    if (len == 0) {
        e = ((r0 == CRF_START) ? __expf(ts0) : 0.f);   // Q0 = onehot(START)
    } else {
        e = q0 * __expf(ts0) + q1 * __expf(ts1);       // invalid lanes: q=0
    }
    float se = wave_sum64(e);

    if (lane == 0) out[b] = LN2F * Lacc + __logf(se);
}

extern "C" void kernel_launch(void* const* d_in, const int* in_sizes, int n_in,
                              void* d_out, int out_size, void* d_ws, size_t ws_size,
                              hipStream_t stream) {
    const float* logits = (const float*)d_in[0];   // [B, T, L] fp32
    const float* trans  = (const float*)d_in[1];   // [L, L] fp32
    const int*   lens   = (const int*)d_in[2];     // [B] int32
    float* out = (float*)d_out;                    // [B] fp32

    const int B = 512;
    const int T = 512;

    crf_forward_kernel<<<dim3(B), dim3(64), 0, stream>>>(
        logits, trans, lens, out, B, T);
}